// Round 1
// baseline (70.305 us; speedup 1.0000x reference)
//
#include <hip/hip_runtime.h>
#include <hip/hip_bf16.h>

#define BATCH 16384
#define FIELDS 50
#define EMB 64
#define HID 200
#define NCOPY 16

// ---------------- K1: gather + FM bi-interaction + partial column stats ----
__global__ __launch_bounds__(256) void k_fm(const int* __restrict__ x,
                                            const float* __restrict__ emb,
                                            float* __restrict__ bi,
                                            float* __restrict__ st1) {
    __shared__ int sidx[4][FIELDS];
    __shared__ float sbi[4][EMB];
    const int tid = threadIdx.x;
    const int r = tid >> 6;        // row within block (one wave per row)
    const int d = tid & 63;        // embedding dim
    const int b = blockIdx.x * 4 + r;

    if (d < FIELDS) sidx[r][d] = x[b * FIELDS + d];
    __syncthreads();

    float s = 0.f, q = 0.f;
#pragma unroll
    for (int f = 0; f < FIELDS; ++f) {
        float v = emb[(size_t)sidx[r][f] * EMB + d];
        s += v;
        q += v * v;
    }
    float v = 0.5f * (s * s - q);
    bi[b * EMB + d] = v;
    sbi[r][d] = v;
    __syncthreads();

    if (r == 0) {
        float a = 0.f, a2 = 0.f;
#pragma unroll
        for (int i = 0; i < 4; ++i) {
            float t = sbi[i][d];
            a += t;
            a2 += t * t;
        }
        float* st = st1 + (blockIdx.x & (NCOPY - 1)) * 128;
        atomicAdd(st + d, a);
        atomicAdd(st + 64 + d, a2);
    }
}

// ---------------- K2: finalize BN1 coefficients (64 dims) ------------------
__global__ void k_fin1(const float* __restrict__ st1,
                       const float* __restrict__ g,
                       const float* __restrict__ be,
                       float* __restrict__ coef) {
    int d = threadIdx.x;  // 64 threads
    float s = 0.f, q = 0.f;
    for (int c = 0; c < NCOPY; ++c) {
        s += st1[c * 128 + d];
        q += st1[c * 128 + 64 + d];
    }
    float mean = s * (1.f / BATCH);
    float var = q * (1.f / BATCH) - mean * mean;
    float a = g[d] * rsqrtf(var + 1e-5f);
    coef[d] = a;
    coef[64 + d] = be[d] - mean * a;
}

// ---------------- K3: h1 = relu(BN1(bi)) @ W1 + b1, + partial stats --------
// block = 256 (4 waves), 32 rows/block (8 rows/wave), grid = 512
__global__ __launch_bounds__(256) void k_fc1(const float* __restrict__ bi,
                                             const float* __restrict__ coef,
                                             const float* __restrict__ w1,
                                             const float* __restrict__ b1,
                                             float* __restrict__ y,
                                             float* __restrict__ st2) {
    __shared__ float w1s[EMB * HID + 64];  // padded tail for lane>=8 j3 reads
    __shared__ float b1s[HID];
    const int tid = threadIdx.x;
    for (int i = tid; i < EMB * HID; i += 256) w1s[i] = w1[i];
    if (tid < 64) w1s[EMB * HID + tid] = 0.f;
    if (tid < HID) b1s[tid] = b1[tid];
    __syncthreads();

    const int l = tid & 63;
    const int w = tid >> 6;
    const float a1 = coef[l];
    const float c1v = coef[64 + l];
    const int base_row = blockIdx.x * 32 + w * 8;

    float z[8];
#pragma unroll
    for (int r = 0; r < 8; ++r) {
        float v = bi[(base_row + r) * EMB + l];
        v = a1 * v + c1v;
        z[r] = v > 0.f ? v : 0.f;
    }

    float acc[8][4];
#pragma unroll
    for (int r = 0; r < 8; ++r)
#pragma unroll
        for (int k = 0; k < 4; ++k) acc[r][k] = 0.f;

#pragma unroll 8
    for (int d = 0; d < EMB; ++d) {
        float w0 = w1s[d * HID + l];
        float wv1 = w1s[d * HID + 64 + l];
        float w2 = w1s[d * HID + 128 + l];
        float w3 = w1s[d * HID + 192 + l];  // only meaningful for l<8 (padded)
#pragma unroll
        for (int r = 0; r < 8; ++r) {
            float zz = __int_as_float(
                __builtin_amdgcn_readlane(__float_as_int(z[r]), d));
            acc[r][0] += zz * w0;
            acc[r][1] += zz * wv1;
            acc[r][2] += zz * w2;
            acc[r][3] += zz * w3;
        }
    }

    // store y (+b1) and accumulate per-lane column stats over the 8 rows
    float s0 = 0.f, s1 = 0.f, s2 = 0.f, s3 = 0.f;
    float q0 = 0.f, q1 = 0.f, q2 = 0.f, q3 = 0.f;
    const float bb0 = b1s[l], bb1 = b1s[64 + l], bb2 = b1s[128 + l];
    const float bb3 = (l < 8) ? b1s[192 + l] : 0.f;
#pragma unroll
    for (int r = 0; r < 8; ++r) {
        int row = base_row + r;
        float v0 = acc[r][0] + bb0;
        float v1 = acc[r][1] + bb1;
        float v2 = acc[r][2] + bb2;
        y[row * HID + l] = v0;
        y[row * HID + 64 + l] = v1;
        y[row * HID + 128 + l] = v2;
        s0 += v0; q0 += v0 * v0;
        s1 += v1; q1 += v1 * v1;
        s2 += v2; q2 += v2 * v2;
        if (l < 8) {
            float v3 = acc[r][3] + bb3;
            y[row * HID + 192 + l] = v3;
            s3 += v3; q3 += v3 * v3;
        }
    }
    float* st = st2 + (blockIdx.x & (NCOPY - 1)) * 400;
    atomicAdd(st + l, s0);
    atomicAdd(st + 200 + l, q0);
    atomicAdd(st + 64 + l, s1);
    atomicAdd(st + 200 + 64 + l, q1);
    atomicAdd(st + 128 + l, s2);
    atomicAdd(st + 200 + 128 + l, q2);
    if (l < 8) {
        atomicAdd(st + 192 + l, s3);
        atomicAdd(st + 200 + 192 + l, q3);
    }
}

// ---------------- K4: finalize BN2 coefficients (200 dims) -----------------
__global__ void k_fin2(const float* __restrict__ st2,
                       const float* __restrict__ g,
                       const float* __restrict__ be,
                       float* __restrict__ coef) {
    int j = threadIdx.x;  // 256 threads, first 200 active
    if (j >= HID) return;
    float s = 0.f, q = 0.f;
    for (int c = 0; c < NCOPY; ++c) {
        s += st2[c * 400 + j];
        q += st2[c * 400 + 200 + j];
    }
    float mean = s * (1.f / BATCH);
    float var = q * (1.f / BATCH) - mean * mean;
    float a = g[j] * rsqrtf(var + 1e-5f);
    coef[j] = a;
    coef[200 + j] = be[j] - mean * a;
}

// ---------------- K5: out = sigmoid(relu(BN2(y)) @ w_last + b_last) --------
// block = 256 (4 waves), 16 rows/block, grid = 1024
__global__ __launch_bounds__(256) void k_out(const float* __restrict__ y,
                                             const float* __restrict__ coef,
                                             const float* __restrict__ wl,
                                             const float* __restrict__ bl,
                                             float* __restrict__ out) {
    const int l = threadIdx.x & 63;
    const int w = threadIdx.x >> 6;
    const int j0 = l, j1 = 64 + l, j2 = 128 + l;
    const int j3 = (l < 8) ? (192 + l) : 199;  // clamped for safety
    const float a0 = coef[j0], c0 = coef[200 + j0];
    const float a1 = coef[j1], c1 = coef[200 + j1];
    const float a2 = coef[j2], c2 = coef[200 + j2];
    const float a3 = coef[j3], c3 = coef[200 + j3];
    const float w0 = wl[j0], w1v = wl[j1], w2 = wl[j2], w3 = wl[j3];
    const float blv = bl[0];

#pragma unroll
    for (int it = 0; it < 4; ++it) {
        int row = blockIdx.x * 16 + it * 4 + w;
        const float* yr = y + row * HID;
        float v0 = a0 * yr[j0] + c0;
        float v1 = a1 * yr[j1] + c1;
        float v2 = a2 * yr[j2] + c2;
        float v3 = a3 * yr[j3] + c3;
        v0 = v0 > 0.f ? v0 : 0.f;
        v1 = v1 > 0.f ? v1 : 0.f;
        v2 = v2 > 0.f ? v2 : 0.f;
        v3 = v3 > 0.f ? v3 : 0.f;
        float t = v0 * w0 + v1 * w1v + v2 * w2 + ((l < 8) ? v3 * w3 : 0.f);
#pragma unroll
        for (int off = 32; off > 0; off >>= 1) t += __shfl_xor(t, off, 64);
        if (l == 0) out[row] = 1.f / (1.f + __expf(-(t + blv)));
    }
}

extern "C" void kernel_launch(void* const* d_in, const int* in_sizes, int n_in,
                              void* d_out, int out_size, void* d_ws, size_t ws_size,
                              hipStream_t stream) {
    const int* x = (const int*)d_in[0];
    const float* emb = (const float*)d_in[1];
    const float* w1 = (const float*)d_in[2];
    const float* b1 = (const float*)d_in[3];
    const float* wl = (const float*)d_in[4];
    const float* bl = (const float*)d_in[5];
    const float* g_bi = (const float*)d_in[6];
    const float* be_bi = (const float*)d_in[7];
    const float* g_h = (const float*)d_in[8];
    const float* be_h = (const float*)d_in[9];
    float* out = (float*)d_out;

    float* ws = (float*)d_ws;
    float* bi = ws;                          // BATCH*64
    float* y = bi + BATCH * EMB;             // BATCH*200
    float* st1 = y + (size_t)BATCH * HID;    // 16*128
    float* st2 = st1 + NCOPY * 128;          // 16*400
    float* c1 = st2 + NCOPY * 400;           // 128
    float* c2 = c1 + 128;                    // 400

    // zero the stats accumulators (graph-capture-safe async memset)
    hipMemsetAsync(st1, 0, (NCOPY * 128 + NCOPY * 400) * sizeof(float), stream);

    k_fm<<<BATCH / 4, 256, 0, stream>>>(x, emb, bi, st1);
    k_fin1<<<1, 64, 0, stream>>>(st1, g_bi, be_bi, c1);
    k_fc1<<<BATCH / 32, 256, 0, stream>>>(bi, c1, w1, b1, y, st2);
    k_fin2<<<1, 256, 0, stream>>>(st2, g_h, be_h, c2);
    k_out<<<BATCH / 16, 256, 0, stream>>>(y, c2, wl, bl, out);
}

// Round 2
// 67.668 us; speedup vs baseline: 1.0390x; 1.0390x over previous
//
#include <hip/hip_runtime.h>
#include <hip/hip_bf16.h>

#define BATCH 16384
#define FIELDS 50
#define EMB 64
#define HID 200
#define NCOPY 16

// ---------------- K1: gather + FM bi-interaction + partial column stats ----
// 256 threads = 16 rows/block; lane c=tid&15 owns dims 4c..4c+3 of row tid>>4.
// Each lane: 50 float4 gathers (coalesced 256B per 16-lane group), lane-local
// FM accumulation, float4 store of bi. BN1 stats via shfl + LDS + atomics.
__global__ __launch_bounds__(256) void k_fm(const int* __restrict__ x,
                                            const float* __restrict__ emb,
                                            float* __restrict__ bi,
                                            float* __restrict__ st1) {
    __shared__ int sidx[16 * FIELDS];
    __shared__ float swave[4][128];
    const int tid = threadIdx.x;
    for (int i = tid; i < 16 * FIELDS; i += 256)
        sidx[i] = x[blockIdx.x * 16 * FIELDS + i];
    __syncthreads();

    const int r = tid >> 4;   // row within block 0..15
    const int c = tid & 15;   // dim group: dims 4c..4c+3
    const int* rowidx = sidx + r * FIELDS;

    float s0 = 0.f, s1 = 0.f, s2 = 0.f, s3 = 0.f;
    float q0 = 0.f, q1 = 0.f, q2 = 0.f, q3 = 0.f;
#pragma unroll 10
    for (int f = 0; f < FIELDS; ++f) {
        const float4 v = *(const float4*)(emb + (size_t)rowidx[f] * EMB + c * 4);
        s0 += v.x; q0 += v.x * v.x;
        s1 += v.y; q1 += v.y * v.y;
        s2 += v.z; q2 += v.z * v.z;
        s3 += v.w; q3 += v.w * v.w;
    }
    float4 o;
    o.x = 0.5f * (s0 * s0 - q0);
    o.y = 0.5f * (s1 * s1 - q1);
    o.z = 0.5f * (s2 * s2 - q2);
    o.w = 0.5f * (s3 * s3 - q3);
    const int row = blockIdx.x * 16 + r;
    *(float4*)(bi + row * EMB + c * 4) = o;

    // ---- BN1 partial stats: sum v and v^2 per dim over this block's 16 rows
    float pv0 = o.x, pv1 = o.y, pv2 = o.z, pv3 = o.w;
    float pq0 = o.x * o.x, pq1 = o.y * o.y, pq2 = o.z * o.z, pq3 = o.w * o.w;
#pragma unroll
    for (int off = 16; off <= 32; off <<= 1) {
        pv0 += __shfl_xor(pv0, off, 64); pq0 += __shfl_xor(pq0, off, 64);
        pv1 += __shfl_xor(pv1, off, 64); pq1 += __shfl_xor(pq1, off, 64);
        pv2 += __shfl_xor(pv2, off, 64); pq2 += __shfl_xor(pq2, off, 64);
        pv3 += __shfl_xor(pv3, off, 64); pq3 += __shfl_xor(pq3, off, 64);
    }
    const int lane = tid & 63;
    const int w = tid >> 6;
    if (lane < 16) {
        float4* sv = (float4*)&swave[w][lane * 4];
        float4* sq = (float4*)&swave[w][64 + lane * 4];
        *sv = make_float4(pv0, pv1, pv2, pv3);
        *sq = make_float4(pq0, pq1, pq2, pq3);
    }
    __syncthreads();
    if (tid < 128) {
        float t = swave[0][tid] + swave[1][tid] + swave[2][tid] + swave[3][tid];
        atomicAdd(st1 + (blockIdx.x & (NCOPY - 1)) * 128 + tid, t);
    }
}

// ---------------- K3: h1 = relu(BN1(bi)) @ W1 + b1, + partial stats --------
// BN1 coefficient finalization folded in (redundant per block, 2K L2 reads).
__global__ __launch_bounds__(256) void k_fc1(const float* __restrict__ bi,
                                             const float* __restrict__ st1,
                                             const float* __restrict__ g_bi,
                                             const float* __restrict__ be_bi,
                                             const float* __restrict__ w1,
                                             const float* __restrict__ b1,
                                             float* __restrict__ y,
                                             float* __restrict__ st2) {
    __shared__ float w1s[EMB * HID + 64];  // padded tail for lane>=8 j3 reads
    __shared__ float b1s[HID];
    __shared__ float c1s[128];
    const int tid = threadIdx.x;
    for (int i = tid; i < EMB * HID; i += 256) w1s[i] = w1[i];
    if (tid < 64) w1s[EMB * HID + tid] = 0.f;
    if (tid < HID) b1s[tid] = b1[tid];
    if (tid < 64) {
        float s = 0.f, q = 0.f;
        for (int cc = 0; cc < NCOPY; ++cc) {
            s += st1[cc * 128 + tid];
            q += st1[cc * 128 + 64 + tid];
        }
        float mean = s * (1.f / BATCH);
        float var = q * (1.f / BATCH) - mean * mean;
        float a = g_bi[tid] * rsqrtf(var + 1e-5f);
        c1s[tid] = a;
        c1s[64 + tid] = be_bi[tid] - mean * a;
    }
    __syncthreads();

    const int l = tid & 63;
    const int w = tid >> 6;
    const float a1 = c1s[l];
    const float c1v = c1s[64 + l];
    const int base_row = blockIdx.x * 32 + w * 8;

    float z[8];
#pragma unroll
    for (int r = 0; r < 8; ++r) {
        float v = bi[(base_row + r) * EMB + l];
        v = a1 * v + c1v;
        z[r] = v > 0.f ? v : 0.f;
    }

    float acc[8][4];
#pragma unroll
    for (int r = 0; r < 8; ++r)
#pragma unroll
        for (int k = 0; k < 4; ++k) acc[r][k] = 0.f;

#pragma unroll 8
    for (int d = 0; d < EMB; ++d) {
        float w0 = w1s[d * HID + l];
        float wv1 = w1s[d * HID + 64 + l];
        float w2 = w1s[d * HID + 128 + l];
        float w3 = w1s[d * HID + 192 + l];  // padded for l>=8
#pragma unroll
        for (int r = 0; r < 8; ++r) {
            float zz = __int_as_float(
                __builtin_amdgcn_readlane(__float_as_int(z[r]), d));
            acc[r][0] += zz * w0;
            acc[r][1] += zz * wv1;
            acc[r][2] += zz * w2;
            acc[r][3] += zz * w3;
        }
    }

    float s0 = 0.f, s1 = 0.f, s2 = 0.f, s3 = 0.f;
    float q0 = 0.f, q1 = 0.f, q2 = 0.f, q3 = 0.f;
    const float bb0 = b1s[l], bb1 = b1s[64 + l], bb2 = b1s[128 + l];
    const float bb3 = (l < 8) ? b1s[192 + l] : 0.f;
#pragma unroll
    for (int r = 0; r < 8; ++r) {
        int row = base_row + r;
        float v0 = acc[r][0] + bb0;
        float v1 = acc[r][1] + bb1;
        float v2 = acc[r][2] + bb2;
        y[row * HID + l] = v0;
        y[row * HID + 64 + l] = v1;
        y[row * HID + 128 + l] = v2;
        s0 += v0; q0 += v0 * v0;
        s1 += v1; q1 += v1 * v1;
        s2 += v2; q2 += v2 * v2;
        if (l < 8) {
            float v3 = acc[r][3] + bb3;
            y[row * HID + 192 + l] = v3;
            s3 += v3; q3 += v3 * v3;
        }
    }
    float* st = st2 + (blockIdx.x & (NCOPY - 1)) * 400;
    atomicAdd(st + l, s0);
    atomicAdd(st + 200 + l, q0);
    atomicAdd(st + 64 + l, s1);
    atomicAdd(st + 200 + 64 + l, q1);
    atomicAdd(st + 128 + l, s2);
    atomicAdd(st + 200 + 128 + l, q2);
    if (l < 8) {
        atomicAdd(st + 192 + l, s3);
        atomicAdd(st + 200 + 192 + l, q3);
    }
}

// ---------------- K5: out = sigmoid(relu(BN2(y)) @ w_last + b_last) --------
// BN2 coefficient finalization folded in (redundant per block, 6.4K L2 reads).
__global__ __launch_bounds__(256) void k_out(const float* __restrict__ y,
                                             const float* __restrict__ st2,
                                             const float* __restrict__ g_h,
                                             const float* __restrict__ be_h,
                                             const float* __restrict__ wl,
                                             const float* __restrict__ bl,
                                             float* __restrict__ out) {
    __shared__ float c2s[400];
    const int tid = threadIdx.x;
    if (tid < HID) {
        float s = 0.f, q = 0.f;
        for (int cc = 0; cc < NCOPY; ++cc) {
            s += st2[cc * 400 + tid];
            q += st2[cc * 400 + 200 + tid];
        }
        float mean = s * (1.f / BATCH);
        float var = q * (1.f / BATCH) - mean * mean;
        float a = g_h[tid] * rsqrtf(var + 1e-5f);
        c2s[tid] = a;
        c2s[200 + tid] = be_h[tid] - mean * a;
    }
    __syncthreads();

    const int l = tid & 63;
    const int w = tid >> 6;
    const int j0 = l, j1 = 64 + l, j2 = 128 + l;
    const int j3 = (l < 8) ? (192 + l) : 199;  // clamped for safety
    const float a0 = c2s[j0], c0 = c2s[200 + j0];
    const float a1 = c2s[j1], c1 = c2s[200 + j1];
    const float a2 = c2s[j2], c2 = c2s[200 + j2];
    const float a3 = c2s[j3], c3 = c2s[200 + j3];
    const float w0 = wl[j0], w1v = wl[j1], w2 = wl[j2], w3 = wl[j3];
    const float blv = bl[0];

#pragma unroll
    for (int it = 0; it < 4; ++it) {
        int row = blockIdx.x * 16 + it * 4 + w;
        const float* yr = y + row * HID;
        float v0 = a0 * yr[j0] + c0;
        float v1 = a1 * yr[j1] + c1;
        float v2 = a2 * yr[j2] + c2;
        float v3 = a3 * yr[j3] + c3;
        v0 = v0 > 0.f ? v0 : 0.f;
        v1 = v1 > 0.f ? v1 : 0.f;
        v2 = v2 > 0.f ? v2 : 0.f;
        v3 = v3 > 0.f ? v3 : 0.f;
        float t = v0 * w0 + v1 * w1v + v2 * w2 + ((l < 8) ? v3 * w3 : 0.f);
#pragma unroll
        for (int off = 32; off > 0; off >>= 1) t += __shfl_xor(t, off, 64);
        if (l == 0) out[row] = 1.f / (1.f + __expf(-(t + blv)));
    }
}

extern "C" void kernel_launch(void* const* d_in, const int* in_sizes, int n_in,
                              void* d_out, int out_size, void* d_ws, size_t ws_size,
                              hipStream_t stream) {
    const int* x = (const int*)d_in[0];
    const float* emb = (const float*)d_in[1];
    const float* w1 = (const float*)d_in[2];
    const float* b1 = (const float*)d_in[3];
    const float* wl = (const float*)d_in[4];
    const float* bl = (const float*)d_in[5];
    const float* g_bi = (const float*)d_in[6];
    const float* be_bi = (const float*)d_in[7];
    const float* g_h = (const float*)d_in[8];
    const float* be_h = (const float*)d_in[9];
    float* out = (float*)d_out;

    float* ws = (float*)d_ws;
    float* bi = ws;                          // BATCH*64
    float* y = bi + BATCH * EMB;             // BATCH*200
    float* st1 = y + (size_t)BATCH * HID;    // 16*128
    float* st2 = st1 + NCOPY * 128;          // 16*400

    hipMemsetAsync(st1, 0, (NCOPY * 128 + NCOPY * 400) * sizeof(float), stream);

    k_fm<<<BATCH / 16, 256, 0, stream>>>(x, emb, bi, st1);
    k_fc1<<<BATCH / 32, 256, 0, stream>>>(bi, st1, g_bi, be_bi, w1, b1, y, st2);
    k_out<<<BATCH / 16, 256, 0, stream>>>(y, st2, g_h, be_h, wl, bl, out);
}